// Round 1
// 2479.932 us; speedup vs baseline: 2.1505x; 2.1505x over previous
//
#include <hip/hip_runtime.h>
#include <hip/hip_bf16.h>
#include <math.h>

// Problem constants
#define B_  32
#define L_  512
#define D_  768
#define H_  12
#define SD_ 5
#define DH_ 64
#define ML_ (B_ * L_)          // 16384 rows
#define CN_ (H_ * (SD_ + 1))   // 72 cond columns

// ---------------------------------------------------------------------------
// Generic fp32 tiled GEMM: C[M,N] = A[M,K] @ W[K,N] + bias[N] (+resid[M,N])
// Optional txt: A_eff[m,k] = A[m,k] + txt[(m>>9), k]  (broadcast over L=512)
// Tile 64x64, K-tile 16, 256 threads, 4x4 micro-tile per thread.
// ---------------------------------------------------------------------------
__global__ __launch_bounds__(256) void gemm_kernel(
    const float* __restrict__ A, const float* __restrict__ W,
    const float* __restrict__ bias, const float* resid,
    const float* txt, float* __restrict__ C,
    int M, int N, int K)
{
    __shared__ float As[16][65];   // [k][m], padded to kill store conflicts
    __shared__ float Bs[16][64];   // [k][n]

    const int tid = threadIdx.x;
    const int tx = tid & 15;       // 0..15  -> n micro
    const int ty = tid >> 4;       // 0..15  -> m micro
    const int m0 = blockIdx.y * 64;
    const int n0 = blockIdx.x * 64;

    const int la_m = tid >> 2;          // 0..63
    const int la_k = (tid & 3) * 4;     // 0,4,8,12
    const int lb_k = tid >> 4;          // 0..15
    const int lb_n = (tid & 15) * 4;    // 0..60

    float acc[4][4];
    #pragma unroll
    for (int i = 0; i < 4; ++i)
        #pragma unroll
        for (int j = 0; j < 4; ++j) acc[i][j] = 0.f;

    for (int k0 = 0; k0 < K; k0 += 16) {
        // A tile
        float4 av = *(const float4*)(A + (size_t)(m0 + la_m) * K + k0 + la_k);
        if (txt) {
            const float* trow = txt + (size_t)((m0 + la_m) >> 9) * K + k0 + la_k;
            av.x += trow[0]; av.y += trow[1]; av.z += trow[2]; av.w += trow[3];
        }
        As[la_k + 0][la_m] = av.x;
        As[la_k + 1][la_m] = av.y;
        As[la_k + 2][la_m] = av.z;
        As[la_k + 3][la_m] = av.w;
        // B tile (guard N for the cond GEMM, N=72)
        if (n0 + lb_n + 3 < N) {
            *(float4*)&Bs[lb_k][lb_n] =
                *(const float4*)(W + (size_t)(k0 + lb_k) * N + n0 + lb_n);
        } else {
            #pragma unroll
            for (int j = 0; j < 4; ++j)
                Bs[lb_k][lb_n + j] = (n0 + lb_n + j < N)
                    ? W[(size_t)(k0 + lb_k) * N + n0 + lb_n + j] : 0.f;
        }
        __syncthreads();

        #pragma unroll
        for (int kk = 0; kk < 16; ++kk) {
            float a[4], b[4];
            #pragma unroll
            for (int i = 0; i < 4; ++i) a[i] = As[kk][ty * 4 + i];
            #pragma unroll
            for (int j = 0; j < 4; ++j) b[j] = Bs[kk][tx * 4 + j];
            #pragma unroll
            for (int i = 0; i < 4; ++i)
                #pragma unroll
                for (int j = 0; j < 4; ++j) acc[i][j] += a[i] * b[j];
        }
        __syncthreads();
    }

    #pragma unroll
    for (int i = 0; i < 4; ++i) {
        const int m = m0 + ty * 4 + i;
        #pragma unroll
        for (int j = 0; j < 4; ++j) {
            const int n = n0 + tx * 4 + j;
            if (n < N) {
                float v = acc[i][j] + bias[n];
                if (resid) v += resid[(size_t)m * N + n];
                C[(size_t)m * N + n] = v;
            }
        }
    }
}

// ---------------------------------------------------------------------------
// Logits: batched tiled QK^T (64x64 tile, k=64) per (b,h), spatial
// sigmoid-log + mask fused in epilogue. Writes logits to `fused` buffer.
// grid: (tt=8, lt=8, b*H+h=384), block 256.
// ---------------------------------------------------------------------------
__global__ __launch_bounds__(256) void logits_kernel(
    const float* __restrict__ qh, const float* __restrict__ kh,
    const float* __restrict__ swb, const float* __restrict__ pl,
    const int* __restrict__ mask, float* __restrict__ fused)
{
    __shared__ float Qs[64][65];   // [k][l]
    __shared__ float Ks[64][65];   // [k][t]
    __shared__ float swl[6][64];   // spatial coeffs per local l row
    __shared__ int   mrow[64];     // mask for this t tile

    const int tid = threadIdx.x;
    const int tt = blockIdx.x;
    const int lt = blockIdx.y;
    const int bh = blockIdx.z;
    const int b  = bh / H_;
    const int h  = bh % H_;

    const int la_m = tid >> 2;          // 0..63
    const int la_k = (tid & 3) << 4;    // 0,16,32,48

    {
        const float* qsrc = qh + (size_t)(b * L_ + lt * 64 + la_m) * D_ + h * DH_ + la_k;
        const float* ksrc = kh + (size_t)(b * L_ + tt * 64 + la_m) * D_ + h * DH_ + la_k;
        #pragma unroll
        for (int c = 0; c < 4; ++c) {
            float4 v = *(const float4*)(qsrc + c * 4);
            Qs[la_k + c * 4 + 0][la_m] = v.x;
            Qs[la_k + c * 4 + 1][la_m] = v.y;
            Qs[la_k + c * 4 + 2][la_m] = v.z;
            Qs[la_k + c * 4 + 3][la_m] = v.w;
            float4 w = *(const float4*)(ksrc + c * 4);
            Ks[la_k + c * 4 + 0][la_m] = w.x;
            Ks[la_k + c * 4 + 1][la_m] = w.y;
            Ks[la_k + c * 4 + 2][la_m] = w.z;
            Ks[la_k + c * 4 + 3][la_m] = w.w;
        }
    }
    for (int i = tid; i < 64 * 6; i += 256) {
        const int r = i / 6, c = i % 6;
        swl[c][r] = swb[(size_t)(b * L_ + lt * 64 + r) * CN_ + h * 6 + c];
    }
    if (tid < 64) mrow[tid] = mask[b * L_ + tt * 64 + tid];
    __syncthreads();

    const int tx = tid & 15;       // -> t micro
    const int ty = tid >> 4;       // -> l micro

    float acc[4][4];
    #pragma unroll
    for (int i = 0; i < 4; ++i)
        #pragma unroll
        for (int j = 0; j < 4; ++j) acc[i][j] = 0.f;

    #pragma unroll 1
    for (int kb = 0; kb < 64; kb += 16) {
        #pragma unroll
        for (int k2 = 0; k2 < 16; ++k2) {
            const int kk = kb + k2;
            float a[4], bb[4];
            #pragma unroll
            for (int i = 0; i < 4; ++i) a[i] = Qs[kk][ty * 4 + i];
            #pragma unroll
            for (int j = 0; j < 4; ++j) bb[j] = Ks[kk][tx * 4 + j];
            #pragma unroll
            for (int i = 0; i < 4; ++i)
                #pragma unroll
                for (int j = 0; j < 4; ++j) acc[i][j] += a[i] * bb[j];
        }
    }

    // Epilogue: spatial bias + sigmoid-log + mask, write logits
    const int t0 = tx * 4;
    #pragma unroll
    for (int i = 0; i < 4; ++i) {
        const int lr = ty * 4 + i;
        const float c0 = swl[0][lr], c1 = swl[1][lr], c2 = swl[2][lr];
        const float c3 = swl[3][lr], c4 = swl[4][lr], c5 = swl[5][lr];
        const float* plrow = pl +
            (((size_t)(b * L_ + lt * 64 + lr)) * L_ + tt * 64 + t0) * SD_;
        float tmp[4];
        #pragma unroll
        for (int j = 0; j < 4; ++j) {
            if (mrow[t0 + j]) {
                tmp[j] = -1e30f;
            } else {
                const float* p = plrow + j * SD_;
                float lv = c0 + c1 * p[0] + c2 * p[1] + c3 * p[2]
                              + c4 * p[3] + c5 * p[4];
                float sig = 1.f / (1.f + expf(-lv));
                sig = fmaxf(sig, 1e-6f);
                tmp[j] = logf(sig) + acc[i][j] * 0.125f;
            }
        }
        float4 res = { tmp[0], tmp[1], tmp[2], tmp[3] };
        *(float4*)(fused + ((size_t)bh * L_ + lt * 64 + lr) * L_ + tt * 64 + t0) = res;
    }
}

// ---------------------------------------------------------------------------
// Softmax over last dim (512), in place on fused. One wave per row.
// grid: 196608 rows / 4 waves = 49152 blocks.
// ---------------------------------------------------------------------------
__global__ __launch_bounds__(256) void softmax_kernel(float* __restrict__ P)
{
    const size_t row = (size_t)blockIdx.x * 4 + (threadIdx.x >> 6);
    const int lane = threadIdx.x & 63;
    float4* rp = (float4*)(P + row * L_);

    float4 a = rp[lane];
    float4 c = rp[lane + 64];
    float m = fmaxf(fmaxf(fmaxf(a.x, a.y), fmaxf(a.z, a.w)),
                    fmaxf(fmaxf(c.x, c.y), fmaxf(c.z, c.w)));
    #pragma unroll
    for (int off = 32; off >= 1; off >>= 1) m = fmaxf(m, __shfl_xor(m, off));

    a.x = expf(a.x - m); a.y = expf(a.y - m);
    a.z = expf(a.z - m); a.w = expf(a.w - m);
    c.x = expf(c.x - m); c.y = expf(c.y - m);
    c.z = expf(c.z - m); c.w = expf(c.w - m);
    float s = a.x + a.y + a.z + a.w + c.x + c.y + c.z + c.w;
    #pragma unroll
    for (int off = 32; off >= 1; off >>= 1) s += __shfl_xor(s, off);
    const float inv = 1.f / s;

    a.x *= inv; a.y *= inv; a.z *= inv; a.w *= inv;
    c.x *= inv; c.y *= inv; c.z *= inv; c.w *= inv;
    rp[lane] = a;
    rp[lane + 64] = c;
}

// ---------------------------------------------------------------------------
// PV: ctx[b,l,h,dh] = sum_t P[b,h,l,t] * vh[b,t,h,dh].
// Batched tiled GEMM, 64x64 out tile, k=512 in 16-chunks.
// grid: (lt=8, b*H+h=384), block 256.
// ---------------------------------------------------------------------------
__global__ __launch_bounds__(256) void pv_kernel(
    const float* __restrict__ P, const float* __restrict__ vh,
    float* __restrict__ ctx)
{
    __shared__ float As[16][65];   // [t][l]
    __shared__ float Bs[16][64];   // [t][dh]

    const int tid = threadIdx.x;
    const int lt = blockIdx.x;
    const int bh = blockIdx.y;
    const int b  = bh / H_;
    const int h  = bh % H_;

    const int tx = tid & 15;
    const int ty = tid >> 4;
    const int la_m = tid >> 2;          // 0..63
    const int la_k = (tid & 3) * 4;     // 0,4,8,12
    const int lb_k = tid >> 4;          // 0..15
    const int lb_n = (tid & 15) * 4;    // 0..60

    float acc[4][4];
    #pragma unroll
    for (int i = 0; i < 4; ++i)
        #pragma unroll
        for (int j = 0; j < 4; ++j) acc[i][j] = 0.f;

    const float* Pbase = P + ((size_t)bh * L_ + lt * 64) * L_;

    for (int k0 = 0; k0 < L_; k0 += 16) {
        float4 av = *(const float4*)(Pbase + (size_t)la_m * L_ + k0 + la_k);
        As[la_k + 0][la_m] = av.x;
        As[la_k + 1][la_m] = av.y;
        As[la_k + 2][la_m] = av.z;
        As[la_k + 3][la_m] = av.w;
        *(float4*)&Bs[lb_k][lb_n] =
            *(const float4*)(vh + (size_t)(b * L_ + k0 + lb_k) * D_ + h * DH_ + lb_n);
        __syncthreads();

        #pragma unroll
        for (int kk = 0; kk < 16; ++kk) {
            float a[4], bb[4];
            #pragma unroll
            for (int i = 0; i < 4; ++i) a[i] = As[kk][ty * 4 + i];
            #pragma unroll
            for (int j = 0; j < 4; ++j) bb[j] = Bs[kk][tx * 4 + j];
            #pragma unroll
            for (int i = 0; i < 4; ++i)
                #pragma unroll
                for (int j = 0; j < 4; ++j) acc[i][j] += a[i] * bb[j];
        }
        __syncthreads();
    }

    #pragma unroll
    for (int i = 0; i < 4; ++i) {
        float4 res = { acc[i][0], acc[i][1], acc[i][2], acc[i][3] };
        *(float4*)(ctx + (size_t)(b * L_ + lt * 64 + ty * 4 + i) * D_
                   + h * DH_ + tx * 4) = res;
    }
}

// ---------------------------------------------------------------------------
// LayerNorm: one block per row of 768.
// ---------------------------------------------------------------------------
__global__ __launch_bounds__(256) void ln_kernel(
    const float* __restrict__ x, const float* __restrict__ scale,
    const float* __restrict__ bias, float* __restrict__ y)
{
    const int row = blockIdx.x;
    const int tid = threadIdx.x;
    const float* xr = x + (size_t)row * D_;

    float v0 = xr[tid], v1 = xr[tid + 256], v2 = xr[tid + 512];
    float s = v0 + v1 + v2;
    #pragma unroll
    for (int off = 32; off >= 1; off >>= 1) s += __shfl_xor(s, off);

    __shared__ float red[4];
    __shared__ float red2[4];
    const int wave = tid >> 6, lane = tid & 63;
    if (lane == 0) red[wave] = s;
    __syncthreads();
    const float mu = (red[0] + red[1] + red[2] + red[3]) * (1.f / 768.f);

    const float d0 = v0 - mu, d1 = v1 - mu, d2 = v2 - mu;
    float sq = d0 * d0 + d1 * d1 + d2 * d2;
    #pragma unroll
    for (int off = 32; off >= 1; off >>= 1) sq += __shfl_xor(sq, off);
    if (lane == 0) red2[wave] = sq;
    __syncthreads();
    const float var = (red2[0] + red2[1] + red2[2] + red2[3]) * (1.f / 768.f);
    const float r = rsqrtf(var + 1e-5f);

    float* yr = y + (size_t)row * D_;
    yr[tid]       = d0 * r * scale[tid]       + bias[tid];
    yr[tid + 256] = d1 * r * scale[tid + 256] + bias[tid + 256];
    yr[tid + 512] = d2 * r * scale[tid + 512] + bias[tid + 512];
}

// ---------------------------------------------------------------------------
extern "C" void kernel_launch(void* const* d_in, const int* in_sizes, int n_in,
                              void* d_out, int out_size, void* d_ws, size_t ws_size,
                              hipStream_t stream) {
    const float* q    = (const float*)d_in[0];
    const float* k    = (const float*)d_in[1];
    const float* v    = (const float*)d_in[2];
    const float* pl   = (const float*)d_in[3];
    const float* txt  = (const float*)d_in[4];
    const int*   mask = (const int*)  d_in[5];
    const float* Wq   = (const float*)d_in[6];
    const float* bq   = (const float*)d_in[7];
    const float* Wk   = (const float*)d_in[8];
    const float* bk   = (const float*)d_in[9];
    const float* Wv   = (const float*)d_in[10];
    const float* bv   = (const float*)d_in[11];
    const float* Wfc  = (const float*)d_in[12];
    const float* bfc  = (const float*)d_in[13];
    const float* Wc   = (const float*)d_in[14];
    const float* bc   = (const float*)d_in[15];
    const float* lns  = (const float*)d_in[16];
    const float* lnb  = (const float*)d_in[17];

    const size_t NE = (size_t)ML_ * D_;      // 12,582,912
    float* qh  = (float*)d_ws;
    float* kh  = qh + NE;
    float* vh  = kh + NE;
    float* swb = vh + NE;                    // 16384*72

    float* y     = (float*)d_out;
    float* fused = y + NE;                   // [B,H,L,L]

    const dim3 blk(256);
    const dim3 gproj(D_ / 64, ML_ / 64);     // (12, 256)
    const dim3 gcond((CN_ + 63) / 64, ML_ / 64);

    gemm_kernel<<<gproj, blk, 0, stream>>>(q, Wq, bq, nullptr, nullptr, qh, ML_, D_, D_);
    gemm_kernel<<<gproj, blk, 0, stream>>>(k, Wk, bk, nullptr, nullptr, kh, ML_, D_, D_);
    gemm_kernel<<<gproj, blk, 0, stream>>>(v, Wv, bv, nullptr, nullptr, vh, ML_, D_, D_);
    gemm_kernel<<<gcond, blk, 0, stream>>>(q, Wc, bc, nullptr, txt, swb, ML_, CN_, D_);

    // logits (QK^T + spatial + mask) -> fused buffer
    logits_kernel<<<dim3(8, 8, B_ * H_), blk, 0, stream>>>(qh, kh, swb, pl, mask, fused);
    // softmax in place on fused
    softmax_kernel<<<dim3((B_ * H_ * L_) / 4), blk, 0, stream>>>(fused);
    // PV -> ctx (reuse qh workspace; qh is dead after logits_kernel)
    pv_kernel<<<dim3(8, B_ * H_), blk, 0, stream>>>(fused, vh, qh);

    // x = ctx @ Wfc + bfc + q  -> reuse kh as x buffer
    gemm_kernel<<<gproj, blk, 0, stream>>>(qh, Wfc, bfc, q, nullptr, kh, ML_, D_, D_);

    ln_kernel<<<dim3(ML_), blk, 0, stream>>>(kh, lns, lnb, y);
}